// Round 2
// baseline (267.649 us; speedup 1.0000x reference)
//
#include <hip/hip_runtime.h>
#include <math.h>

// Problem constants (fixed by setup_inputs)
#define Nn 32
#define Cc 128
#define Ss 4096
#define Kk 64
#define NCHUNK 32
#define SCHUNK (Ss / NCHUNK)   // 128 pixels per block
#define ST 64                  // pixels per subtile
#define NSUB (SCHUNK / ST)     // 2 subtiles per block
#define BLK 256
#define XSTR 68                // x_lds row stride (floats): 16B-aligned, 2-way banks
#define ASTR 68                // a_lds row stride (floats)

// Fused: per-pixel L2-norm -> 1x1 conv logits -> softmax -> VLAD partial GEMM.
// vlad[n][k][c] partials and asum[n][k] accumulated via atomicAdd into d_ws.
// LDS = 53504 B -> 3 blocks/CU; __launch_bounds__(256,3) caps VGPR ~168.
__global__ __launch_bounds__(BLK, 3) void netvlad_main(
    const float* __restrict__ x,
    const float* __restrict__ conv_w,
    const float* __restrict__ conv_b,
    float* __restrict__ vlad,
    float* __restrict__ asum)
{
    __shared__ __align__(16) float x_lds[Cc * XSTR];  // [c][s]  128x68
    __shared__ __align__(16) float a_lds[ST * ASTR];  // [s][k]  64x68
    __shared__ float red[ST][4];                      // shared m/s reduce buffer
    __shared__ float invn[ST];

    const int t  = threadIdx.x;
    const int n  = blockIdx.y;
    const int kg = t >> 4;     // VLAD: k = 4*kg+kk
    const int sg = t & 15;     // VLAD: c = sg+16j
    const int p  = t >> 2;     // norm/softmax pixel
    const int ii = t & 3;
    const int wv = __builtin_amdgcn_readfirstlane(t >> 6); // wave id -> uniform k-range
    const int lane = t & 63;   // logits: s = lane

    float acc[4][8];           // vlad partials [kk][cj]
#pragma unroll
    for (int a1 = 0; a1 < 4; ++a1)
#pragma unroll
        for (int b1 = 0; b1 < 8; ++b1) acc[a1][b1] = 0.f;
    float asum_part[16];       // raw softmax sums for k = ii+4j
#pragma unroll
    for (int j = 0; j < 16; ++j) asum_part[j] = 0.f;

    const float* xn    = x + (size_t)n * Cc * Ss;
    const float* wbase = conv_w + wv * 16 * Cc;   // wave-uniform -> s_load path

    for (int sub = 0; sub < NSUB; ++sub) {
        const int s0 = blockIdx.x * SCHUNK + sub * ST;
        __syncthreads();  // prior subtile's LDS reads done

        // ---- stage x tile: 128c x 64s (float4, coalesced) ----
#pragma unroll
        for (int r = 0; r < 8; ++r) {
            int idx4 = t + BLK * r;
            int c    = idx4 >> 4;
            int sq   = (idx4 & 15) << 2;
            float4 v = *(const float4*)(xn + (size_t)c * Ss + s0 + sq);
            *(float4*)&x_lds[c * XSTR + sq] = v;
        }
        __syncthreads();

        // ---- per-pixel inverse norm over C ----
        {
            float ssq = 0.f;
#pragma unroll
            for (int j = 0; j < 32; ++j) {
                float v = x_lds[(ii + 4 * j) * XSTR + p];
                ssq += v * v;
            }
            red[p][ii] = ssq;
        }
        __syncthreads();
        if (ii == 0) {
            float tot = red[p][0] + red[p][1] + red[p][2] + red[p][3];
            invn[p] = 1.0f / fmaxf(sqrtf(tot), 1e-12f);
        }
        __syncthreads();

        // ---- logits: wave wv owns k=16wv..16wv+15, thread owns s=lane ----
        {
            float lg[16];
#pragma unroll
            for (int i = 0; i < 16; ++i) lg[i] = 0.f;

#pragma unroll 8
            for (int c0 = 0; c0 < Cc; c0 += 4) {
                float xv0 = x_lds[(c0 + 0) * XSTR + lane];
                float xv1 = x_lds[(c0 + 1) * XSTR + lane];
                float xv2 = x_lds[(c0 + 2) * XSTR + lane];
                float xv3 = x_lds[(c0 + 3) * XSTR + lane];
#pragma unroll
                for (int i = 0; i < 16; ++i) {
                    float4 w4 = *(const float4*)(wbase + i * Cc + c0); // uniform
                    lg[i] += w4.x * xv0 + w4.y * xv1 + w4.z * xv2 + w4.w * xv3;
                }
            }
            float iv = invn[lane];
#pragma unroll
            for (int i4 = 0; i4 < 4; ++i4) {
                float4 o;
                o.x = lg[4 * i4 + 0] * iv + conv_b[wv * 16 + 4 * i4 + 0];
                o.y = lg[4 * i4 + 1] * iv + conv_b[wv * 16 + 4 * i4 + 1];
                o.z = lg[4 * i4 + 2] * iv + conv_b[wv * 16 + 4 * i4 + 2];
                o.w = lg[4 * i4 + 3] * iv + conv_b[wv * 16 + 4 * i4 + 3];
                *(float4*)&a_lds[lane * ASTR + wv * 16 + 4 * i4] = o;
            }
        }
        __syncthreads();

        // ---- softmax over k per pixel p; thread covers k = ii + 4j ----
        {
            float l[16];
#pragma unroll
            for (int j = 0; j < 16; ++j) l[j] = a_lds[p * ASTR + ii + 4 * j];
            float m = l[0];
#pragma unroll
            for (int j = 1; j < 16; ++j) m = fmaxf(m, l[j]);
            red[p][ii] = m;
            __syncthreads();
            float m4 = fmaxf(fmaxf(red[p][0], red[p][1]),
                             fmaxf(red[p][2], red[p][3]));
            float e[16];
            float ls = 0.f;
#pragma unroll
            for (int j = 0; j < 16; ++j) { e[j] = __expf(l[j] - m4); ls += e[j]; }
            __syncthreads();          // WAR: m-reads done before reusing red
            red[p][ii] = ls;
            __syncthreads();
            float tot  = red[p][0] + red[p][1] + red[p][2] + red[p][3];
            float itot = 1.0f / tot;
            float sca  = itot * invn[p];   // fold invn: a' = a*invn
#pragma unroll
            for (int j = 0; j < 16; ++j) {
                asum_part[j] += e[j] * itot;
                a_lds[p * ASTR + ii + 4 * j] = e[j] * sca;
            }
        }
        __syncthreads();

        // ---- vlad accumulate, all-b128: acc[kk][j] += a'[s][4kg+kk]*x[sg+16j][s]
#pragma unroll 2
        for (int s4 = 0; s4 < 16; ++s4) {
            float4 a0 = *(const float4*)&a_lds[(4 * s4 + 0) * ASTR + 4 * kg];
            float4 a1 = *(const float4*)&a_lds[(4 * s4 + 1) * ASTR + 4 * kg];
            float4 a2 = *(const float4*)&a_lds[(4 * s4 + 2) * ASTR + 4 * kg];
            float4 a3 = *(const float4*)&a_lds[(4 * s4 + 3) * ASTR + 4 * kg];
#pragma unroll
            for (int j = 0; j < 8; ++j) {
                float4 x4 = *(const float4*)&x_lds[(sg + 16 * j) * XSTR + 4 * s4];
                acc[0][j] += a0.x * x4.x + a1.x * x4.y + a2.x * x4.z + a3.x * x4.w;
                acc[1][j] += a0.y * x4.x + a1.y * x4.y + a2.y * x4.z + a3.y * x4.w;
                acc[2][j] += a0.z * x4.x + a1.z * x4.y + a2.z * x4.z + a3.z * x4.w;
                acc[3][j] += a0.w * x4.x + a1.w * x4.y + a2.w * x4.z + a3.w * x4.w;
            }
        }
    }

    // ---- commit vlad partials ----
    float* vbase = vlad + ((size_t)n * Kk + 4 * kg) * Cc + sg;
#pragma unroll
    for (int kk = 0; kk < 4; ++kk)
#pragma unroll
        for (int j = 0; j < 8; ++j)
            atomicAdd(vbase + kk * Cc + 16 * j, acc[kk][j]);

    // ---- block-reduce asum then one atomic per k ----
    __syncthreads();  // a_lds dead now
#pragma unroll
    for (int j = 0; j < 16; ++j) a_lds[p * ASTR + ii + 4 * j] = asum_part[j];
    __syncthreads();
    if (t < Kk) {
        float s_ = 0.f;
        for (int p2 = 0; p2 < ST; ++p2) s_ += a_lds[p2 * ASTR + t];
        atomicAdd(&asum[n * Kk + t], s_);
    }
}

// Parallel finalize: one block per n. Phase 1: per-(k) intra-norm scale via
// 4-thread teams + LDS reduce. Phase 2: out[n][c] = sum_k scale*(vlad-as*cent).
__global__ __launch_bounds__(256) void netvlad_final(
    const float* __restrict__ vlad, const float* __restrict__ asum,
    const float* __restrict__ centroids, const float* __restrict__ fc_w,
    float* __restrict__ out)
{
    __shared__ float scale_s[Kk];
    __shared__ float asum_s[Kk];
    __shared__ float red2[Kk][4];

    const int n = blockIdx.x;
    const int t = threadIdx.x;
    const int k = t >> 2;      // 0..63
    const int q = t & 3;       // c-quarter

    const float* vr = vlad + ((size_t)n * Kk + k) * Cc + q * 32;
    const float* cr = centroids + k * Cc + q * 32;
    const float  as = asum[n * Kk + k];

    float ssq = 0.f;
#pragma unroll
    for (int i = 0; i < 8; ++i) {
        float4 v4 = *(const float4*)(vr + 4 * i);
        float4 c4 = *(const float4*)(cr + 4 * i);
        float d0 = v4.x - as * c4.x;
        float d1 = v4.y - as * c4.y;
        float d2 = v4.z - as * c4.z;
        float d3 = v4.w - as * c4.w;
        ssq += d0 * d0 + d1 * d1 + d2 * d2 + d3 * d3;
    }
    red2[k][q] = ssq;
    __syncthreads();
    if (q == 0) {
        float tot = red2[k][0] + red2[k][1] + red2[k][2] + red2[k][3];
        scale_s[k] = fc_w[k] / fmaxf(sqrtf(tot), 1e-12f);
        asum_s[k]  = as;
    }
    __syncthreads();

    if (t < Cc) {
        const int c = t;
        const float* vb = vlad + (size_t)n * Kk * Cc + c;
        float o = 0.f;
#pragma unroll 8
        for (int k2 = 0; k2 < Kk; ++k2)
            o += scale_s[k2] * (vb[k2 * Cc] - asum_s[k2] * centroids[k2 * Cc + c]);
        out[n * Cc + c] = o;
    }
}

extern "C" void kernel_launch(void* const* d_in, const int* in_sizes, int n_in,
                              void* d_out, int out_size, void* d_ws, size_t ws_size,
                              hipStream_t stream) {
    (void)in_sizes; (void)n_in; (void)out_size; (void)ws_size;
    const float* x         = (const float*)d_in[0];
    const float* conv_w    = (const float*)d_in[1];
    const float* conv_b    = (const float*)d_in[2];
    const float* centroids = (const float*)d_in[3];
    const float* fc_w      = (const float*)d_in[4];
    float* out = (float*)d_out;

    float* vlad = (float*)d_ws;                         // [N][K][C] = 1 MB
    float* asum = vlad + (size_t)Nn * Kk * Cc;          // [N][K]    = 8 KB
    size_t zero_bytes = ((size_t)Nn * Kk * Cc + (size_t)Nn * Kk) * sizeof(float);
    hipMemsetAsync(d_ws, 0, zero_bytes, stream);        // ws is poisoned 0xAA each call

    dim3 grid(NCHUNK, Nn);
    netvlad_main<<<grid, BLK, 0, stream>>>(x, conv_w, conv_b, vlad, asum);
    netvlad_final<<<Nn, 256, 0, stream>>>(vlad, asum, centroids, fc_w, out);
}

// Round 3
// 170.021 us; speedup vs baseline: 1.5742x; 1.5742x over previous
//
#include <hip/hip_runtime.h>
#include <math.h>

// Problem constants (fixed by setup_inputs)
#define Nn 32
#define Cc 128
#define Ss 4096
#define Kk 64
#define NCHUNK 16
#define SCHUNK (Ss / NCHUNK)   // 256 pixels per block
#define ST 64                  // pixels per subtile
#define NSUB (SCHUNK / ST)     // 4 subtiles per block
#define BLK 256
#define XSTR 68                // x_lds row stride (floats): 16B-aligned, bank-friendly
#define ASTR 68                // a_lds row stride (floats)

// Fused: per-pixel L2-norm -> 1x1 conv logits -> softmax -> VLAD partial GEMM.
// vlad[n][k][c] partials and asum[n][k] accumulated via atomicAdd into d_ws.
// R1 structure (88 us) + R2's b128 VLAD inner loop. Logits keep per-thread
// 4k x 4s register tile with per-lane conv_w float4 loads (L2-resident, 32 KB).
__global__ __launch_bounds__(BLK, 2) void netvlad_main(
    const float* __restrict__ x,
    const float* __restrict__ conv_w,
    const float* __restrict__ conv_b,
    float* __restrict__ vlad,
    float* __restrict__ asum)
{
    __shared__ __align__(16) float x_lds[Cc * XSTR];  // [c][s]  128x68
    __shared__ __align__(16) float a_lds[ST * ASTR];  // [s][k]  64x68
    __shared__ float red_m[ST][4];
    __shared__ float red_s[ST][4];
    __shared__ float invn[ST];

    const int t  = threadIdx.x;
    const int n  = blockIdx.y;
    const int kg = t >> 4;     // 0..15 : k = 4*kg+kk (logits & vlad)
    const int sg = t & 15;     // 0..15 : s = 4*sg+ss (logits); c = sg+16j (vlad)
    const int p  = t >> 2;     // 0..63 pixel (norm / softmax)
    const int ii = t & 3;      // 0..3

    float acc[4][8];           // vlad partials: [kk][cj]
#pragma unroll
    for (int a1 = 0; a1 < 4; ++a1)
#pragma unroll
        for (int b1 = 0; b1 < 8; ++b1) acc[a1][b1] = 0.f;
    float asum_part[16];       // raw softmax sums for k = ii+4j
#pragma unroll
    for (int j = 0; j < 16; ++j) asum_part[j] = 0.f;

    const float* xn = x + (size_t)n * Cc * Ss;

    for (int sub = 0; sub < NSUB; ++sub) {
        const int s0 = blockIdx.x * SCHUNK + sub * ST;
        __syncthreads();  // prior subtile's vlad reads of x_lds/a_lds done

        // ---- stage x tile: 128 c x 64 s (float4, coalesced 64B runs) ----
#pragma unroll
        for (int r = 0; r < 8; ++r) {
            int idx4 = t + BLK * r;            // 0..2047 float4s
            int c    = idx4 >> 4;              // 0..127
            int sq   = (idx4 & 15) << 2;       // 0..60
            float4 v = *(const float4*)(xn + (size_t)c * Ss + s0 + sq);
            *(float4*)&x_lds[c * XSTR + sq] = v;
        }
        __syncthreads();

        // ---- per-pixel inverse norm over C ----
        {
            float ssq = 0.f;
#pragma unroll
            for (int j = 0; j < 32; ++j) {
                float v = x_lds[(ii + 4 * j) * XSTR + p];
                ssq += v * v;
            }
            red_m[p][ii] = ssq;
        }
        __syncthreads();
        if (ii == 0) {
            float tot = red_m[p][0] + red_m[p][1] + red_m[p][2] + red_m[p][3];
            invn[p] = 1.0f / fmaxf(sqrtf(tot), 1e-12f);
        }
        __syncthreads();

        // ---- logits: l[kk][ss] = sum_c w[k][c]*x[c][s];  4k x 4s per thread ----
        {
            float l[4][4];
#pragma unroll
            for (int a1 = 0; a1 < 4; ++a1)
#pragma unroll
                for (int b1 = 0; b1 < 4; ++b1) l[a1][b1] = 0.f;

#pragma unroll 4
            for (int c0 = 0; c0 < Cc; c0 += 4) {
                float wv[4][4];
#pragma unroll
                for (int kk = 0; kk < 4; ++kk) {
                    float4 w4 = *(const float4*)(conv_w + (4 * kg + kk) * Cc + c0);
                    wv[kk][0] = w4.x; wv[kk][1] = w4.y; wv[kk][2] = w4.z; wv[kk][3] = w4.w;
                }
                float xv[4][4];
#pragma unroll
                for (int cc = 0; cc < 4; ++cc) {
                    float4 x4 = *(const float4*)&x_lds[(c0 + cc) * XSTR + 4 * sg];
                    xv[cc][0] = x4.x; xv[cc][1] = x4.y; xv[cc][2] = x4.z; xv[cc][3] = x4.w;
                }
#pragma unroll
                for (int kk = 0; kk < 4; ++kk)
#pragma unroll
                    for (int ss2 = 0; ss2 < 4; ++ss2)
#pragma unroll
                        for (int cc = 0; cc < 4; ++cc)
                            l[kk][ss2] += wv[kk][cc] * xv[cc][ss2];
            }
            // epilogue: scale by invn (x was raw), add bias, write raw logits
            float binv[4];
#pragma unroll
            for (int ss2 = 0; ss2 < 4; ++ss2) binv[ss2] = invn[4 * sg + ss2];
            float bk[4];
#pragma unroll
            for (int kk = 0; kk < 4; ++kk) bk[kk] = conv_b[4 * kg + kk];
#pragma unroll
            for (int ss2 = 0; ss2 < 4; ++ss2) {
                float4 o;
                o.x = l[0][ss2] * binv[ss2] + bk[0];
                o.y = l[1][ss2] * binv[ss2] + bk[1];
                o.z = l[2][ss2] * binv[ss2] + bk[2];
                o.w = l[3][ss2] * binv[ss2] + bk[3];
                *(float4*)&a_lds[(4 * sg + ss2) * ASTR + 4 * kg] = o;
            }
        }
        __syncthreads();

        // ---- softmax over k per pixel p; thread covers k = ii + 4j ----
        {
            float l[16];
#pragma unroll
            for (int j = 0; j < 16; ++j) l[j] = a_lds[p * ASTR + ii + 4 * j];
            float m = l[0];
#pragma unroll
            for (int j = 1; j < 16; ++j) m = fmaxf(m, l[j]);
            red_m[p][ii] = m;
            __syncthreads();
            float m4 = fmaxf(fmaxf(red_m[p][0], red_m[p][1]),
                             fmaxf(red_m[p][2], red_m[p][3]));
            float e[16];
            float ls = 0.f;
#pragma unroll
            for (int j = 0; j < 16; ++j) { e[j] = __expf(l[j] - m4); ls += e[j]; }
            red_s[p][ii] = ls;
            __syncthreads();
            float tot  = red_s[p][0] + red_s[p][1] + red_s[p][2] + red_s[p][3];
            float itot = 1.0f / tot;
            float sca  = itot * invn[p];   // fold invn: a' = a * invn -> a'*x = a*xf
#pragma unroll
            for (int j = 0; j < 16; ++j) {
                asum_part[j] += e[j] * itot;               // raw a for centroid term
                a_lds[p * ASTR + ii + 4 * j] = e[j] * sca; // a' for vlad GEMM
            }
        }
        __syncthreads();

        // ---- vlad accumulate, all-b128: acc[kk][j] += a'[s][4kg+kk]*x[sg+16j][s]
#pragma unroll 2
        for (int s4 = 0; s4 < 16; ++s4) {
            float4 a0 = *(const float4*)&a_lds[(4 * s4 + 0) * ASTR + 4 * kg];
            float4 a1 = *(const float4*)&a_lds[(4 * s4 + 1) * ASTR + 4 * kg];
            float4 a2 = *(const float4*)&a_lds[(4 * s4 + 2) * ASTR + 4 * kg];
            float4 a3 = *(const float4*)&a_lds[(4 * s4 + 3) * ASTR + 4 * kg];
#pragma unroll
            for (int j = 0; j < 8; ++j) {
                float4 x4 = *(const float4*)&x_lds[(sg + 16 * j) * XSTR + 4 * s4];
                acc[0][j] += a0.x * x4.x + a1.x * x4.y + a2.x * x4.z + a3.x * x4.w;
                acc[1][j] += a0.y * x4.x + a1.y * x4.y + a2.y * x4.z + a3.y * x4.w;
                acc[2][j] += a0.z * x4.x + a1.z * x4.y + a2.z * x4.z + a3.z * x4.w;
                acc[3][j] += a0.w * x4.x + a1.w * x4.y + a2.w * x4.z + a3.w * x4.w;
            }
        }
    }

    // ---- commit vlad partials (16 chunk-blocks contend per address) ----
    float* vbase = vlad + ((size_t)n * Kk + 4 * kg) * Cc + sg;
#pragma unroll
    for (int kk = 0; kk < 4; ++kk)
#pragma unroll
        for (int j = 0; j < 8; ++j)
            atomicAdd(vbase + kk * Cc + 16 * j, acc[kk][j]);

    // ---- block-reduce asum then one atomic per k ----
    __syncthreads();  // a_lds dead now
#pragma unroll
    for (int j = 0; j < 16; ++j) a_lds[p * ASTR + ii + 4 * j] = asum_part[j];
    __syncthreads();
    if (t < Kk) {
        float s_ = 0.f;
        for (int p2 = 0; p2 < ST; ++p2) s_ += a_lds[p2 * ASTR + t];
        atomicAdd(&asum[n * Kk + t], s_);
    }
}

// Parallel finalize: one block per n. Phase 1: per-k intra-norm scale via
// 4-thread teams + LDS reduce. Phase 2: out[n][c] = sum_k scale*(vlad-as*cent).
__global__ __launch_bounds__(256) void netvlad_final(
    const float* __restrict__ vlad, const float* __restrict__ asum,
    const float* __restrict__ centroids, const float* __restrict__ fc_w,
    float* __restrict__ out)
{
    __shared__ float scale_s[Kk];
    __shared__ float asum_s[Kk];
    __shared__ float red2[Kk][4];

    const int n = blockIdx.x;
    const int t = threadIdx.x;
    const int k = t >> 2;      // 0..63
    const int q = t & 3;       // c-quarter

    const float* vr = vlad + ((size_t)n * Kk + k) * Cc + q * 32;
    const float* cr = centroids + k * Cc + q * 32;
    const float  as = asum[n * Kk + k];

    float ssq = 0.f;
#pragma unroll
    for (int i = 0; i < 8; ++i) {
        float4 v4 = *(const float4*)(vr + 4 * i);
        float4 c4 = *(const float4*)(cr + 4 * i);
        float d0 = v4.x - as * c4.x;
        float d1 = v4.y - as * c4.y;
        float d2 = v4.z - as * c4.z;
        float d3 = v4.w - as * c4.w;
        ssq += d0 * d0 + d1 * d1 + d2 * d2 + d3 * d3;
    }
    red2[k][q] = ssq;
    __syncthreads();
    if (q == 0) {
        float tot = red2[k][0] + red2[k][1] + red2[k][2] + red2[k][3];
        scale_s[k] = fc_w[k] / fmaxf(sqrtf(tot), 1e-12f);
        asum_s[k]  = as;
    }
    __syncthreads();

    if (t < Cc) {
        const int c = t;
        const float* vb = vlad + (size_t)n * Kk * Cc + c;
        float o = 0.f;
#pragma unroll 8
        for (int k2 = 0; k2 < Kk; ++k2)
            o += scale_s[k2] * (vb[k2 * Cc] - asum_s[k2] * centroids[k2 * Cc + c]);
        out[n * Cc + c] = o;
    }
}

extern "C" void kernel_launch(void* const* d_in, const int* in_sizes, int n_in,
                              void* d_out, int out_size, void* d_ws, size_t ws_size,
                              hipStream_t stream) {
    (void)in_sizes; (void)n_in; (void)out_size; (void)ws_size;
    const float* x         = (const float*)d_in[0];
    const float* conv_w    = (const float*)d_in[1];
    const float* conv_b    = (const float*)d_in[2];
    const float* centroids = (const float*)d_in[3];
    const float* fc_w      = (const float*)d_in[4];
    float* out = (float*)d_out;

    float* vlad = (float*)d_ws;                         // [N][K][C] = 1 MB
    float* asum = vlad + (size_t)Nn * Kk * Cc;          // [N][K]    = 8 KB
    size_t zero_bytes = ((size_t)Nn * Kk * Cc + (size_t)Nn * Kk) * sizeof(float);
    hipMemsetAsync(d_ws, 0, zero_bytes, stream);        // ws is poisoned 0xAA each call

    dim3 grid(NCHUNK, Nn);
    netvlad_main<<<grid, BLK, 0, stream>>>(x, conv_w, conv_b, vlad, asum);
    netvlad_final<<<Nn, 256, 0, stream>>>(vlad, asum, centroids, fc_w, out);
}

// Round 4
// 119.343 us; speedup vs baseline: 2.2427x; 1.4246x over previous
//
#include <hip/hip_runtime.h>
#include <math.h>

// Problem constants (fixed by setup_inputs)
#define Nn 32
#define Cc 128
#define Ss 4096
#define Kk 64
#define NCHUNK 16
#define SCHUNK (Ss / NCHUNK)   // 256 pixels per block
#define ST 64                  // pixels per subtile
#define NSUB (SCHUNK / ST)     // 4 subtiles per block
#define BLK 256

// LDS strides (chosen for 16B-aligned fragment reads + even bank spread)
#define XCS 72    // xC [c][s] stride in ushorts (s-contig rows, 36 dw, 16B-aligned)
#define XTS 136   // xT [s][c] stride in ushorts (c-contig rows, 68 dw, 16B-aligned)
#define LKS 68    // Lbuf [s][k] stride in floats (aliases xT region: 68 dw == 136 u16)
#define AS  72    // aB [k][s] stride in ushorts
#define RS  17    // red stride in floats (odd -> conflict-free column reads)

typedef __attribute__((ext_vector_type(8))) short short8;   // bf16x8 MFMA frag
typedef __attribute__((ext_vector_type(4))) float float4v;  // fp32x4 MFMA acc

__device__ __forceinline__ unsigned f2bf(float f) {
    unsigned u = __builtin_bit_cast(unsigned, f);
    return (u + 0x7fffu + ((u >> 16) & 1u)) >> 16;   // RNE f32->bf16
}
__device__ __forceinline__ unsigned pack2(float a, float b) {
    return f2bf(a) | (f2bf(b) << 16);
}

// Fused: stage bf16 x (2 layouts) -> L2-norm -> MFMA logits -> softmax ->
// MFMA VLAD (persistent AGPR/VGPR acc) -> atomic commit.
// MFMA 16x16x32 bf16 layouts (HW-verified per guide):
//   A[m=lane&15][k=quad*8+j], B[k=quad*8+j][n=lane&15], D col=lane&15 row=4*quad+reg.
__global__ __launch_bounds__(BLK, 2) void netvlad_main(
    const float* __restrict__ x,
    const float* __restrict__ conv_w,
    const float* __restrict__ conv_b,
    float* __restrict__ vlad,
    float* __restrict__ asum)
{
    __shared__ __align__(16) unsigned short xC[Cc * XCS];  // 18432 B raw-x bf16 [c][s]
    __shared__ __align__(16) float Lbuf[ST * LKS];         // 17408 B logits [s][k] / xT alias
    __shared__ __align__(16) unsigned short aB[Kk * AS];   // 9216 B  a' bf16 [k][s]
    __shared__ float red[ST * RS];                         // 4352 B  ssq partials
    __shared__ float invn[ST];
    unsigned short* xT = (unsigned short*)Lbuf;            // raw-x bf16 [s][c]

    const int t    = threadIdx.x;
    const int n    = blockIdx.y;
    const int w    = t >> 6;      // wave id: k-rows 16w..16w+15
    const int l    = t & 63;
    const int m    = l & 15;
    const int quad = l >> 4;
    const int p    = t >> 2;      // softmax pixel
    const int ii   = t & 3;       // softmax k-slice

    // ---- one-time: conv_w A-fragments (bf16, regs) + bias for D rows ----
    short8 wfrag[4];
    {
        const float* wr_ = conv_w + (16 * w + m) * Cc;
#pragma unroll
        for (int ks = 0; ks < 4; ++ks) {
            float4 wa = *(const float4*)(wr_ + 32 * ks + 8 * quad);
            float4 wb = *(const float4*)(wr_ + 32 * ks + 8 * quad + 4);
            union { short8 s8; unsigned u[4]; } W_;
            W_.u[0] = pack2(wa.x, wa.y);
            W_.u[1] = pack2(wa.z, wa.w);
            W_.u[2] = pack2(wb.x, wb.y);
            W_.u[3] = pack2(wb.z, wb.w);
            wfrag[ks] = W_.s8;
        }
    }
    float bias_r[4];
#pragma unroll
    for (int r = 0; r < 4; ++r) bias_r[r] = conv_b[16 * w + 4 * quad + r];

    float4v acc[8];               // VLAD acc: 16k x 128c per wave, persistent
#pragma unroll
    for (int nt = 0; nt < 8; ++nt) acc[nt] = (float4v){0.f, 0.f, 0.f, 0.f};
    float asum_part[16];
#pragma unroll
    for (int j = 0; j < 16; ++j) asum_part[j] = 0.f;

    const float* xn = x + (size_t)n * Cc * Ss;

    for (int sub = 0; sub < NSUB; ++sub) {
        const int s0 = blockIdx.x * SCHUNK + sub * ST;
        __syncthreads();  // prior GEMM2 reads of xC/aB done

        // ---- stage: fp32 load -> ssq partials + bf16 xC [c][s] ----
        {
            float sp0 = 0.f, sp1 = 0.f, sp2 = 0.f, sp3 = 0.f;
            const int sq = (t & 15) << 2;
#pragma unroll
            for (int r = 0; r < 8; ++r) {
                int c = (t >> 4) + 16 * r;
                float4 v = *(const float4*)(xn + (size_t)c * Ss + s0 + sq);
                sp0 += v.x * v.x; sp1 += v.y * v.y;
                sp2 += v.z * v.z; sp3 += v.w * v.w;
                uint2 pk = make_uint2(pack2(v.x, v.y), pack2(v.z, v.w));
                *(uint2*)&xC[c * XCS + sq] = pk;
            }
            red[(sq + 0) * RS + (t >> 4)] = sp0;
            red[(sq + 1) * RS + (t >> 4)] = sp1;
            red[(sq + 2) * RS + (t >> 4)] = sp2;
            red[(sq + 3) * RS + (t >> 4)] = sp3;
        }
        __syncthreads();

        // ---- invn (t<64) ----
        if (t < ST) {
            float tot = 0.f;
#pragma unroll
            for (int i = 0; i < 16; ++i) tot += red[t * RS + i];
            invn[t] = 1.0f / fmaxf(sqrtf(tot), 1e-12f);
        }
        // ---- build xT [s][c] from xC (16B writes; lane-spread over s) ----
        {
            int s = t & 63, oct0 = t >> 6;
#pragma unroll
            for (int q = 0; q < 4; ++q) {
                int oct = oct0 + 4 * q;   // c-octet 0..15
                uint4 dd;
                dd.x = (unsigned)xC[(8 * oct + 0) * XCS + s] | ((unsigned)xC[(8 * oct + 1) * XCS + s] << 16);
                dd.y = (unsigned)xC[(8 * oct + 2) * XCS + s] | ((unsigned)xC[(8 * oct + 3) * XCS + s] << 16);
                dd.z = (unsigned)xC[(8 * oct + 4) * XCS + s] | ((unsigned)xC[(8 * oct + 5) * XCS + s] << 16);
                dd.w = (unsigned)xC[(8 * oct + 6) * XCS + s] | ((unsigned)xC[(8 * oct + 7) * XCS + s] << 16);
                *(uint4*)&xT[s * XTS + 8 * oct] = dd;
            }
        }
        __syncthreads();

        // ---- GEMM1 (MFMA): L[16w+ k][s] = W x rawX, wave does 4 s-tiles x 4 c-steps
        float4v Lr[4];
#pragma unroll
        for (int nt = 0; nt < 4; ++nt) Lr[nt] = (float4v){0.f, 0.f, 0.f, 0.f};
#pragma unroll
        for (int nt = 0; nt < 4; ++nt) {
#pragma unroll
            for (int ks = 0; ks < 4; ++ks) {
                short8 b = *(const short8*)&xT[(16 * nt + m) * XTS + 32 * ks + 8 * quad];
                Lr[nt] = __builtin_amdgcn_mfma_f32_16x16x32_bf16(wfrag[ks], b, Lr[nt], 0, 0, 0);
            }
        }
        __syncthreads();  // all xT reads done -> safe to overwrite with Lbuf

        // epilogue: *invn[s] + bias[k]; write [s][k] fp32
#pragma unroll
        for (int nt = 0; nt < 4; ++nt) {
            float iv = invn[16 * nt + m];
            float4 o;
            o.x = Lr[nt].x * iv + bias_r[0];
            o.y = Lr[nt].y * iv + bias_r[1];
            o.z = Lr[nt].z * iv + bias_r[2];
            o.w = Lr[nt].w * iv + bias_r[3];
            *(float4*)&Lbuf[(16 * nt + m) * LKS + 16 * w + 4 * quad] = o;
        }
        __syncthreads();

        // ---- softmax over k per pixel p (4-thread team via shfl) ----
        {
            float lv[16];
#pragma unroll
            for (int j = 0; j < 16; ++j) lv[j] = Lbuf[p * LKS + ii + 4 * j];
            float mx = lv[0];
#pragma unroll
            for (int j = 1; j < 16; ++j) mx = fmaxf(mx, lv[j]);
            mx = fmaxf(mx, __shfl_xor(mx, 1));
            mx = fmaxf(mx, __shfl_xor(mx, 2));
            float e[16];
            float lsum = 0.f;
#pragma unroll
            for (int j = 0; j < 16; ++j) { e[j] = __expf(lv[j] - mx); lsum += e[j]; }
            lsum += __shfl_xor(lsum, 1);
            lsum += __shfl_xor(lsum, 2);
            float itot = 1.0f / lsum;
            float sca  = itot * invn[p];   // fold invn into a' (x in GEMM2 is raw)
#pragma unroll
            for (int j = 0; j < 16; ++j) {
                float av = e[j] * itot;
                asum_part[j] += av;                               // raw a for centroid term
                aB[(ii + 4 * j) * AS + p] = (unsigned short)f2bf(e[j] * sca);
            }
        }
        __syncthreads();

        // ---- GEMM2 (MFMA): V[16w+k][c] += a'[k][s] x rawX^T[s][c] ----
#pragma unroll
        for (int ks = 0; ks < 2; ++ks) {
            short8 af = *(const short8*)&aB[(16 * w + m) * AS + 32 * ks + 8 * quad];
#pragma unroll
            for (int nt = 0; nt < 8; ++nt) {
                short8 bf_ = *(const short8*)&xC[(16 * nt + m) * XCS + 32 * ks + 8 * quad];
                acc[nt] = __builtin_amdgcn_mfma_f32_16x16x32_bf16(af, bf_, acc[nt], 0, 0, 0);
            }
        }
    }

    // ---- commit vlad partials: lane holds D[k=16w+4quad+r][c=16nt+m] ----
    float* vb = vlad + ((size_t)n * Kk + 16 * w + 4 * quad) * Cc + m;
#pragma unroll
    for (int nt = 0; nt < 8; ++nt) {
        atomicAdd(vb + 0 * Cc + 16 * nt, acc[nt].x);
        atomicAdd(vb + 1 * Cc + 16 * nt, acc[nt].y);
        atomicAdd(vb + 2 * Cc + 16 * nt, acc[nt].z);
        atomicAdd(vb + 3 * Cc + 16 * nt, acc[nt].w);
    }

    // ---- block-reduce asum then one atomic per k (reuse Lbuf) ----
    __syncthreads();
#pragma unroll
    for (int j = 0; j < 16; ++j) Lbuf[p * LKS + ii + 4 * j] = asum_part[j];
    __syncthreads();
    if (t < Kk) {
        float s_ = 0.f;
        for (int p2 = 0; p2 < ST; ++p2) s_ += Lbuf[p2 * LKS + t];
        atomicAdd(&asum[n * Kk + t], s_);
    }
}

// Parallel finalize: one block per n. Phase 1: per-k intra-norm scale via
// 4-thread teams + LDS reduce. Phase 2: out[n][c] = sum_k scale*(vlad-as*cent).
__global__ __launch_bounds__(256) void netvlad_final(
    const float* __restrict__ vlad, const float* __restrict__ asum,
    const float* __restrict__ centroids, const float* __restrict__ fc_w,
    float* __restrict__ out)
{
    __shared__ float scale_s[Kk];
    __shared__ float asum_s[Kk];
    __shared__ float red2[Kk][4];

    const int n = blockIdx.x;
    const int t = threadIdx.x;
    const int k = t >> 2;
    const int q = t & 3;

    const float* vr = vlad + ((size_t)n * Kk + k) * Cc + q * 32;
    const float* cr = centroids + k * Cc + q * 32;
    const float  as = asum[n * Kk + k];

    float ssq = 0.f;
#pragma unroll
    for (int i = 0; i < 8; ++i) {
        float4 v4 = *(const float4*)(vr + 4 * i);
        float4 c4 = *(const float4*)(cr + 4 * i);
        float d0 = v4.x - as * c4.x;
        float d1 = v4.y - as * c4.y;
        float d2 = v4.z - as * c4.z;
        float d3 = v4.w - as * c4.w;
        ssq += d0 * d0 + d1 * d1 + d2 * d2 + d3 * d3;
    }
    red2[k][q] = ssq;
    __syncthreads();
    if (q == 0) {
        float tot = red2[k][0] + red2[k][1] + red2[k][2] + red2[k][3];
        scale_s[k] = fc_w[k] / fmaxf(sqrtf(tot), 1e-12f);
        asum_s[k]  = as;
    }
    __syncthreads();

    if (t < Cc) {
        const int c = t;
        const float* vbp = vlad + (size_t)n * Kk * Cc + c;
        float o = 0.f;
#pragma unroll 8
        for (int k2 = 0; k2 < Kk; ++k2)
            o += scale_s[k2] * (vbp[k2 * Cc] - asum_s[k2] * centroids[k2 * Cc + c]);
        out[n * Cc + c] = o;
    }
}

extern "C" void kernel_launch(void* const* d_in, const int* in_sizes, int n_in,
                              void* d_out, int out_size, void* d_ws, size_t ws_size,
                              hipStream_t stream) {
    (void)in_sizes; (void)n_in; (void)out_size; (void)ws_size;
    const float* x         = (const float*)d_in[0];
    const float* conv_w    = (const float*)d_in[1];
    const float* conv_b    = (const float*)d_in[2];
    const float* centroids = (const float*)d_in[3];
    const float* fc_w      = (const float*)d_in[4];
    float* out = (float*)d_out;

    float* vlad = (float*)d_ws;                         // [N][K][C] = 1 MB
    float* asum = vlad + (size_t)Nn * Kk * Cc;          // [N][K]    = 8 KB
    size_t zero_bytes = ((size_t)Nn * Kk * Cc + (size_t)Nn * Kk) * sizeof(float);
    hipMemsetAsync(d_ws, 0, zero_bytes, stream);        // ws is poisoned 0xAA each call

    dim3 grid(NCHUNK, Nn);
    netvlad_main<<<grid, BLK, 0, stream>>>(x, conv_w, conv_b, vlad, asum);
    netvlad_final<<<Nn, 256, 0, stream>>>(vlad, asum, centroids, fc_w, out);
}